// Round 4
// baseline (3791.431 us; speedup 1.0000x reference)
//
#include <hip/hip_runtime.h>
#include <hip/hip_bf16.h>

#define B_SZ 4
#define N_SZ 4096
#define D_SZ 1024
#define H_SZ 16
#define M_SZ 256
#define DH_SZ 64
#define ROWS (B_SZ * N_SZ)          // 16384
#define SPLIT 8                     // split-K chunks for kv accumulation
#define CH3 8                       // n-chunks for attention-out kernel
#define KV_TOT (B_SZ * H_SZ * M_SZ * DH_SZ)   // 1048576
#define KS_TOT (B_SZ * H_SZ * M_SZ)           // 16384

struct bf4 { __hip_bfloat16 x, y, z, w; };   // 8-byte bf16 quad

// ---------------------------------------------------------------------------
// GEMM1: C_bf16[Mr,Nc] = A_f32[Mr,K] @ B_f32[K,Nc] + bias
// 64x64 tile, BK=16, 256 threads, 4x4 micro-tile. All math f32.
// ---------------------------------------------------------------------------
__global__ __launch_bounds__(256) void gemm_f32_bf16out(
    const float* __restrict__ A, const float* __restrict__ Bm,
    const float* __restrict__ bias, __hip_bfloat16* __restrict__ C,
    int Nc, int K)
{
    __shared__ float As[16][65];   // transposed A tile, padded
    __shared__ float Bs[16][64];
    const int t  = threadIdx.x;
    const int tx = t & 15, ty = t >> 4;
    const long brow = (long)blockIdx.y * 64;
    const long bcol = (long)blockIdx.x * 64;
    const int ar = t >> 2, ac = (t & 3) << 2;
    const int br = t >> 4, bc = (t & 15) << 2;

    float acc[4][4] = {};
    for (int k0 = 0; k0 < K; k0 += 16) {
        float4 av = *(const float4*)(A + (brow + ar) * (long)K + k0 + ac);
        As[ac + 0][ar] = av.x;
        As[ac + 1][ar] = av.y;
        As[ac + 2][ar] = av.z;
        As[ac + 3][ar] = av.w;
        *(float4*)(&Bs[br][bc]) =
            *(const float4*)(Bm + (long)(k0 + br) * Nc + bcol + bc);
        __syncthreads();
        #pragma unroll
        for (int kk = 0; kk < 16; ++kk) {
            const float a0 = As[kk][(ty << 2) + 0];
            const float a1 = As[kk][(ty << 2) + 1];
            const float a2 = As[kk][(ty << 2) + 2];
            const float a3 = As[kk][(ty << 2) + 3];
            const float4 bq = *(const float4*)(&Bs[kk][tx << 2]);
            acc[0][0] += a0 * bq.x; acc[0][1] += a0 * bq.y;
            acc[0][2] += a0 * bq.z; acc[0][3] += a0 * bq.w;
            acc[1][0] += a1 * bq.x; acc[1][1] += a1 * bq.y;
            acc[1][2] += a1 * bq.z; acc[1][3] += a1 * bq.w;
            acc[2][0] += a2 * bq.x; acc[2][1] += a2 * bq.y;
            acc[2][2] += a2 * bq.z; acc[2][3] += a2 * bq.w;
            acc[3][0] += a3 * bq.x; acc[3][1] += a3 * bq.y;
            acc[3][2] += a3 * bq.z; acc[3][3] += a3 * bq.w;
        }
        __syncthreads();
    }
    const float4 bv = *(const float4*)(bias + bcol + (tx << 2));
    #pragma unroll
    for (int i = 0; i < 4; ++i) {
        bf4 o;
        o.x = __float2bfloat16(acc[i][0] + bv.x);
        o.y = __float2bfloat16(acc[i][1] + bv.y);
        o.z = __float2bfloat16(acc[i][2] + bv.z);
        o.w = __float2bfloat16(acc[i][3] + bv.w);
        *(bf4*)(C + (brow + (ty << 2) + i) * (long)Nc + bcol + (tx << 2)) = o;
    }
}

// ---------------------------------------------------------------------------
// GEMM2: C_f32[Mr,Nc] = A_bf16[Mr,K] @ B_f32[K,Nc] + bias. All math f32.
// ---------------------------------------------------------------------------
__global__ __launch_bounds__(256) void gemm_bf16A_f32out(
    const __hip_bfloat16* __restrict__ A, const float* __restrict__ Bm,
    const float* __restrict__ bias, float* __restrict__ C,
    int Nc, int K)
{
    __shared__ float As[16][65];
    __shared__ float Bs[16][64];
    const int t  = threadIdx.x;
    const int tx = t & 15, ty = t >> 4;
    const long brow = (long)blockIdx.y * 64;
    const long bcol = (long)blockIdx.x * 64;
    const int ar = t >> 2, ac = (t & 3) << 2;
    const int br = t >> 4, bc = (t & 15) << 2;

    float acc[4][4] = {};
    for (int k0 = 0; k0 < K; k0 += 16) {
        bf4 av = *(const bf4*)(A + (brow + ar) * (long)K + k0 + ac);
        As[ac + 0][ar] = __bfloat162float(av.x);
        As[ac + 1][ar] = __bfloat162float(av.y);
        As[ac + 2][ar] = __bfloat162float(av.z);
        As[ac + 3][ar] = __bfloat162float(av.w);
        *(float4*)(&Bs[br][bc]) =
            *(const float4*)(Bm + (long)(k0 + br) * Nc + bcol + bc);
        __syncthreads();
        #pragma unroll
        for (int kk = 0; kk < 16; ++kk) {
            const float a0 = As[kk][(ty << 2) + 0];
            const float a1 = As[kk][(ty << 2) + 1];
            const float a2 = As[kk][(ty << 2) + 2];
            const float a3 = As[kk][(ty << 2) + 3];
            const float4 bq = *(const float4*)(&Bs[kk][tx << 2]);
            acc[0][0] += a0 * bq.x; acc[0][1] += a0 * bq.y;
            acc[0][2] += a0 * bq.z; acc[0][3] += a0 * bq.w;
            acc[1][0] += a1 * bq.x; acc[1][1] += a1 * bq.y;
            acc[1][2] += a1 * bq.z; acc[1][3] += a1 * bq.w;
            acc[2][0] += a2 * bq.x; acc[2][1] += a2 * bq.y;
            acc[2][2] += a2 * bq.z; acc[2][3] += a2 * bq.w;
            acc[3][0] += a3 * bq.x; acc[3][1] += a3 * bq.y;
            acc[3][2] += a3 * bq.z; acc[3][3] += a3 * bq.w;
        }
        __syncthreads();
    }
    const float4 bv = *(const float4*)(bias + bcol + (tx << 2));
    #pragma unroll
    for (int i = 0; i < 4; ++i) {
        float4 o;
        o.x = acc[i][0] + bv.x; o.y = acc[i][1] + bv.y;
        o.z = acc[i][2] + bv.z; o.w = acc[i][3] + bv.w;
        *(float4*)(C + (brow + (ty << 2) + i) * (long)Nc + bcol + (tx << 2)) = o;
    }
}

// ---------------------------------------------------------------------------
// Kernel 2: per (b,h,chunk) accumulate k_v[m][dh] and k_sum[m].
// thread t = feature index m; omega column and kv row in registers.
// ---------------------------------------------------------------------------
__global__ __launch_bounds__(256) void kv_accum(
    const __hip_bfloat16* __restrict__ qkv, const float* __restrict__ omega,
    float* __restrict__ kvpart, float* __restrict__ kspart)
{
    const int t  = threadIdx.x;              // m
    const int s  = blockIdx.x % SPLIT;
    const int bh = blockIdx.x / SPLIT;
    const int b  = bh / H_SZ, h = bh % H_SZ;
    __shared__ float row[136];               // [0:64) krow, [64:128) vrow, [128] norm

    float omr[DH_SZ];
    #pragma unroll
    for (int j = 0; j < DH_SZ; ++j) omr[j] = omega[j * M_SZ + t];
    float kvreg[DH_SZ];
    #pragma unroll
    for (int d = 0; d < DH_SZ; ++d) kvreg[d] = 0.f;
    float ks = 0.f;

    const int RPC = N_SZ / SPLIT;            // 512
    const int n0  = s * RPC;
    for (int r = 0; r < RPC; ++r) {
        const long base = ((long)(b * N_SZ + n0 + r)) * (3 * D_SZ);
        __syncthreads();
        if (t < 64) {
            const float kval = __bfloat162float(qkv[base + D_SZ + h * DH_SZ + t]);
            row[t] = kval;
            float ss = kval * kval;
            #pragma unroll
            for (int o = 32; o > 0; o >>= 1) ss += __shfl_xor(ss, o, 64);
            if (t == 0) row[128] = ss;
        } else if (t < 128) {
            row[t] = __bfloat162float(qkv[base + 2 * D_SZ + h * DH_SZ + (t - 64)]);
        }
        __syncthreads();
        const float nrm = row[128];
        float dot = 0.f;
        #pragma unroll
        for (int j = 0; j < DH_SZ; ++j) dot += row[j] * omr[j];
        const float kp = __expf(dot - 0.5f * nrm);
        ks += kp;
        #pragma unroll
        for (int d = 0; d < DH_SZ; ++d) kvreg[d] += kp * row[64 + d];
    }
    float* outp = kvpart + ((long)blockIdx.x * M_SZ + t) * DH_SZ;
    #pragma unroll
    for (int d = 0; d < DH_SZ; d += 4) {
        float4 o = {kvreg[d], kvreg[d + 1], kvreg[d + 2], kvreg[d + 3]};
        *(float4*)(outp + d) = o;
    }
    kspart[(long)blockIdx.x * M_SZ + t] = ks;
}

// ---------------------------------------------------------------------------
// Kernel 2b: reduce SPLIT partials -> kvfin [bh][m][dh], ksfin [bh][m]
// ---------------------------------------------------------------------------
__global__ __launch_bounds__(256) void reduce_parts(
    const float* __restrict__ kvpart, const float* __restrict__ kspart,
    float* __restrict__ kvfin, float* __restrict__ ksfin)
{
    const int i = blockIdx.x * 256 + threadIdx.x;
    if (i < KV_TOT) {
        const int bh  = i / (M_SZ * DH_SZ);
        const int rem = i % (M_SZ * DH_SZ);
        float sum = 0.f;
        #pragma unroll
        for (int p = 0; p < SPLIT; ++p)
            sum += kvpart[((long)(bh * SPLIT + p)) * (M_SZ * DH_SZ) + rem];
        kvfin[i] = sum;
    } else {
        const int j = i - KV_TOT;
        if (j < KS_TOT) {
            const int bh = j / M_SZ;
            const int m  = j % M_SZ;
            float sum = 0.f;
            #pragma unroll
            for (int p = 0; p < SPLIT; ++p)
                sum += kspart[(bh * SPLIT + p) * M_SZ + m];
            ksfin[j] = sum;
        }
    }
}

// ---------------------------------------------------------------------------
// Kernel 3: q' feature map + numerator/denominator -> att bf16 [16384,1024]
// ---------------------------------------------------------------------------
__global__ __launch_bounds__(256) void attn_out(
    const __hip_bfloat16* __restrict__ qkv, const float* __restrict__ omega,
    const float* __restrict__ kvfin, const float* __restrict__ ksfin,
    __hip_bfloat16* __restrict__ att)
{
    const int t  = threadIdx.x;
    const int c  = blockIdx.x % CH3;
    const int bh = blockIdx.x / CH3;
    const int b  = bh / H_SZ, h = bh % H_SZ;
    __shared__ float kvs[M_SZ * (DH_SZ + 1)];   // padded stride 65
    __shared__ float kss[M_SZ];
    __shared__ float qps[M_SZ];
    __shared__ float pnum[M_SZ];
    __shared__ float row[132];
    __shared__ float wsum[4];

    float omr[DH_SZ];
    #pragma unroll
    for (int j = 0; j < DH_SZ; ++j) omr[j] = omega[j * M_SZ + t];
    for (int i = t; i < M_SZ * DH_SZ; i += 256)
        kvs[(i >> 6) * 65 + (i & 63)] = kvfin[(long)bh * (M_SZ * DH_SZ) + i];
    kss[t] = ksfin[bh * M_SZ + t];

    const int RPC = N_SZ / CH3;   // 512
    const int n0  = c * RPC;
    const int d = t & 63, p = t >> 6;
    for (int r = 0; r < RPC; ++r) {
        const long nrow = (long)(b * N_SZ + n0 + r);
        const long base = nrow * (3 * D_SZ);
        __syncthreads();   // also covers initial staging on r==0
        if (t < 64) {
            const float qv = __bfloat162float(qkv[base + h * DH_SZ + t]);
            row[t] = qv;
            float ss = qv * qv;
            #pragma unroll
            for (int o = 32; o > 0; o >>= 1) ss += __shfl_xor(ss, o, 64);
            if (t == 0) row[128] = ss;
        }
        __syncthreads();
        const float nrm = row[128];
        float dot = 0.f;
        #pragma unroll
        for (int j = 0; j < DH_SZ; ++j) dot += row[j] * omr[j];
        const float qp = __expf(dot - 0.5f * nrm);
        qps[t] = qp;
        float pd = qp * kss[t];
        #pragma unroll
        for (int o = 32; o > 0; o >>= 1) pd += __shfl_xor(pd, o, 64);
        if ((t & 63) == 0) wsum[t >> 6] = pd;
        __syncthreads();
        float sacc = 0.f;
        const int m0 = p << 6;
        #pragma unroll 16
        for (int mm = 0; mm < 64; ++mm)
            sacc += qps[m0 + mm] * kvs[(m0 + mm) * 65 + d];
        pnum[t] = sacc;
        __syncthreads();
        if (t < 64) {
            const float den = wsum[0] + wsum[1] + wsum[2] + wsum[3] + 1e-6f;
            const float num = pnum[t] + pnum[t + 64] + pnum[t + 128] + pnum[t + 192];
            att[nrow * D_SZ + h * DH_SZ + t] = __float2bfloat16(num / den);
        }
    }
}

// ---------------------------------------------------------------------------
// Workspace layout (bytes):
//   [0,               100663296)  qkv  bf16  [16384,3072]
//   [100663296,       104857600)  kvfin f32  [64,256,64]
//   [104857600,       104923136)  ksfin f32  [64,256]
//   [104923136,       139001856)  X region:
//        kvpart f32 33,554,432 B + kspart f32 524,288 B   (dead after reduce)
//        att bf16   33,554,432 B                           (aliases partials)
// total 139,001,856 B  (was 272.7 MB -> suspected ws overflow crash)
// ---------------------------------------------------------------------------
extern "C" void kernel_launch(void* const* d_in, const int* in_sizes, int n_in,
                              void* d_out, int out_size, void* d_ws, size_t ws_size,
                              hipStream_t stream)
{
    const float* x     = (const float*)d_in[0];   // [4,4096,1024]
    const float* Wqkv  = (const float*)d_in[1];   // [1024,3072]
    const float* bqkv  = (const float*)d_in[2];   // [3072]
    const float* Wout  = (const float*)d_in[3];   // [1024,1024]
    const float* bout  = (const float*)d_in[4];   // [1024]
    const float* omega = (const float*)d_in[5];   // [64,256]
    float* out = (float*)d_out;

    char* w = (char*)d_ws;
    __hip_bfloat16* qkv = (__hip_bfloat16*)w;
    float* kvfin  = (float*)(w + 100663296);
    float* ksfin  = (float*)(w + 104857600);
    char*  xbuf   = w + 104923136;
    float* kvpart = (float*)xbuf;
    float* kspart = (float*)(xbuf + 33554432);
    __hip_bfloat16* att = (__hip_bfloat16*)xbuf;

    // 1) qkv = x @ Wqkv + bqkv   (f32 math, bf16 store)
    {
        dim3 g(3072 / 64, ROWS / 64);
        gemm_f32_bf16out<<<g, 256, 0, stream>>>(x, Wqkv, bqkv, qkv, 3072, 1024);
    }
    // 2) k' accumulation (split over n) + reduce
    kv_accum<<<B_SZ * H_SZ * SPLIT, 256, 0, stream>>>(qkv, omega, kvpart, kspart);
    {
        int total = KV_TOT + KS_TOT;
        reduce_parts<<<(total + 255) / 256, 256, 0, stream>>>(kvpart, kspart, kvfin, ksfin);
    }
    // 3) q' feature map + numerator/denominator -> att (bf16)
    attn_out<<<B_SZ * H_SZ * CH3, 256, 0, stream>>>(qkv, omega, kvfin, ksfin, att);
    // 4) out = att @ Wout + bout  (f32 out)
    {
        dim3 g(1024 / 64, ROWS / 64);
        gemm_bf16A_f32out<<<g, 256, 0, stream>>>(att, Wout, bout, out, 1024, 1024);
    }
}

// Round 5
// 1875.160 us; speedup vs baseline: 2.0219x; 2.0219x over previous
//
#include <hip/hip_runtime.h>
#include <hip/hip_bf16.h>

#define B_SZ 4
#define N_SZ 4096
#define D_SZ 1024
#define H_SZ 16
#define M_SZ 256
#define DH_SZ 64
#define ROWS (B_SZ * N_SZ)          // 16384
#define SPLIT 8
#define CH3 8
#define KV_TOT (B_SZ * H_SZ * M_SZ * DH_SZ)   // 1048576
#define KS_TOT (B_SZ * H_SZ * M_SZ)           // 16384

typedef unsigned short u16;
typedef __attribute__((ext_vector_type(8))) short bf16x8;
typedef __attribute__((ext_vector_type(4))) float f32x4;

static __device__ inline u16 f2bf(float f) {
    __hip_bfloat16 h = __float2bfloat16(f);
    return *reinterpret_cast<u16*>(&h);
}

static __device__ inline void gl_lds16(const void* g, void* l) {
    void* gg = const_cast<void*>(g);
    __builtin_amdgcn_global_load_lds(
        (__attribute__((address_space(1))) void*)gg,
        (__attribute__((address_space(3))) void*)l, 16, 0, 0);
}

// ---------------------------------------------------------------------------
// convert f32 -> bf16 (8 elements/thread, exact grid)
// ---------------------------------------------------------------------------
__global__ __launch_bounds__(256) void cvt_f32_bf16(
    const float* __restrict__ src, u16* __restrict__ dst)
{
    const long i = ((long)blockIdx.x * 256 + threadIdx.x) * 8;
    float4 v0 = *(const float4*)(src + i);
    float4 v1 = *(const float4*)(src + i + 4);
    union { u16 s[8]; bf16x8 v; } o;
    o.s[0] = f2bf(v0.x); o.s[1] = f2bf(v0.y); o.s[2] = f2bf(v0.z); o.s[3] = f2bf(v0.w);
    o.s[4] = f2bf(v1.x); o.s[5] = f2bf(v1.y); o.s[6] = f2bf(v1.z); o.s[7] = f2bf(v1.w);
    *(bf16x8*)(dst + i) = o.v;
}

// ---------------------------------------------------------------------------
// transpose + convert: src f32 [R][C] -> dst bf16 [C][R]
// ---------------------------------------------------------------------------
__global__ __launch_bounds__(256) void transpose_cvt(
    const float* __restrict__ src, u16* __restrict__ dst, int R, int C)
{
    __shared__ float tile[32][33];
    const int c0 = blockIdx.x * 32, r0 = blockIdx.y * 32;
    const int tx = threadIdx.x & 31, ty = threadIdx.x >> 5;   // 32 x 8
    #pragma unroll
    for (int p = 0; p < 4; ++p)
        tile[ty + 8 * p][tx] = src[(long)(r0 + ty + 8 * p) * C + c0 + tx];
    __syncthreads();
    #pragma unroll
    for (int p = 0; p < 4; ++p)
        dst[(long)(c0 + ty + 8 * p) * R + r0 + tx] = f2bf(tile[tx][ty + 8 * p]);
}

// ---------------------------------------------------------------------------
// MFMA GEMM (m97 structure): C[M,Nc] = A[M,K] @ Bt[Nc,K]^T + bias
// A, Bt bf16 row-major. 128x128 tile, BK=32, 256 thr (4 waves, 64x64/wave).
// ---------------------------------------------------------------------------
template <typename OUT>
__global__ __launch_bounds__(256) void gemm_mfma_bt(
    const u16* __restrict__ A, const u16* __restrict__ Bt,
    const float* __restrict__ bias, OUT* __restrict__ C,
    int Nc, int K)
{
    __shared__ u16 As[128 * 32];   // [row][k] 8 KB
    __shared__ u16 Bs[128 * 32];   // [col][k] 8 KB
    const int t = threadIdx.x;
    const int w = t >> 6, l = t & 63;
    const int wr = w >> 1, wc = w & 1;
    const long brow = (long)blockIdx.y * 128;
    const long bcol = (long)blockIdx.x * 128;

    // staging: 8 x 1KB chunks per tile; wave w does chunks {w, w+4} of each
    const int sr = l >> 2;            // row within 16-row group
    const int sc = (l & 3) * 8;       // k element offset (0,8,16,24)
    const u16* aS0 = A + (brow + w * 16 + sr) * (long)K + sc;
    const u16* aS1 = A + (brow + 64 + w * 16 + sr) * (long)K + sc;
    const u16* bS0 = Bt + (bcol + w * 16 + sr) * (long)K + sc;
    const u16* bS1 = Bt + (bcol + 64 + w * 16 + sr) * (long)K + sc;
    u16* aD0 = As + (w) * 512;        // 512 elems = 1KB
    u16* aD1 = As + (w + 4) * 512;
    u16* bD0 = Bs + (w) * 512;
    u16* bD1 = Bs + (w + 4) * 512;

    f32x4 acc[4][4];
    #pragma unroll
    for (int m = 0; m < 4; ++m)
        #pragma unroll
        for (int n = 0; n < 4; ++n)
            acc[m][n] = (f32x4){0.f, 0.f, 0.f, 0.f};

    const int fr = l & 15;            // fragment row/col
    const int fk = (l >> 4) * 8;      // fragment k offset

    for (int k0 = 0; k0 < K; k0 += 32) {
        __syncthreads();
        gl_lds16(aS0 + k0, aD0);
        gl_lds16(aS1 + k0, aD1);
        gl_lds16(bS0 + k0, bD0);
        gl_lds16(bS1 + k0, bD1);
        __syncthreads();
        bf16x8 af[4], bfv[4];
        #pragma unroll
        for (int m = 0; m < 4; ++m)
            af[m] = *(const bf16x8*)(As + (wr * 64 + m * 16 + fr) * 32 + fk);
        #pragma unroll
        for (int n = 0; n < 4; ++n)
            bfv[n] = *(const bf16x8*)(Bs + (wc * 64 + n * 16 + fr) * 32 + fk);
        #pragma unroll
        for (int m = 0; m < 4; ++m)
            #pragma unroll
            for (int n = 0; n < 4; ++n)
                acc[m][n] = __builtin_amdgcn_mfma_f32_16x16x32_bf16(
                    af[m], bfv[n], acc[m][n], 0, 0, 0);
    }

    // epilogue: D row = (l>>4)*4 + reg, col = l&15   [m89-verified]
    const int fq = l >> 4;
    float bv[4];
    #pragma unroll
    for (int n = 0; n < 4; ++n)
        bv[n] = bias[bcol + wc * 64 + n * 16 + fr];
    #pragma unroll
    for (int m = 0; m < 4; ++m) {
        #pragma unroll
        for (int n = 0; n < 4; ++n) {
            const long col = bcol + wc * 64 + n * 16 + fr;
            #pragma unroll
            for (int r = 0; r < 4; ++r) {
                const long row = brow + wr * 64 + m * 16 + fq * 4 + r;
                const float v = acc[m][n][r] + bv[n];
                if constexpr (sizeof(OUT) == 2)
                    ((u16*)C)[row * Nc + col] = f2bf(v);
                else
                    ((float*)C)[row * Nc + col] = v;
            }
        }
    }
}

// ---------------------------------------------------------------------------
// Kernel 2: per (b,h,chunk) accumulate k_v[m][dh] and k_sum[m]. (unchanged)
// ---------------------------------------------------------------------------
__global__ __launch_bounds__(256) void kv_accum(
    const __hip_bfloat16* __restrict__ qkv, const float* __restrict__ omega,
    float* __restrict__ kvpart, float* __restrict__ kspart)
{
    const int t  = threadIdx.x;              // m
    const int s  = blockIdx.x % SPLIT;
    const int bh = blockIdx.x / SPLIT;
    const int b  = bh / H_SZ, h = bh % H_SZ;
    __shared__ float row[136];

    float omr[DH_SZ];
    #pragma unroll
    for (int j = 0; j < DH_SZ; ++j) omr[j] = omega[j * M_SZ + t];
    float kvreg[DH_SZ];
    #pragma unroll
    for (int d = 0; d < DH_SZ; ++d) kvreg[d] = 0.f;
    float ks = 0.f;

    const int RPC = N_SZ / SPLIT;            // 512
    const int n0  = s * RPC;
    for (int r = 0; r < RPC; ++r) {
        const long base = ((long)(b * N_SZ + n0 + r)) * (3 * D_SZ);
        __syncthreads();
        if (t < 64) {
            const float kval = __bfloat162float(qkv[base + D_SZ + h * DH_SZ + t]);
            row[t] = kval;
            float ss = kval * kval;
            #pragma unroll
            for (int o = 32; o > 0; o >>= 1) ss += __shfl_xor(ss, o, 64);
            if (t == 0) row[128] = ss;
        } else if (t < 128) {
            row[t] = __bfloat162float(qkv[base + 2 * D_SZ + h * DH_SZ + (t - 64)]);
        }
        __syncthreads();
        const float nrm = row[128];
        float dot = 0.f;
        #pragma unroll
        for (int j = 0; j < DH_SZ; ++j) dot += row[j] * omr[j];
        const float kp = __expf(dot - 0.5f * nrm);
        ks += kp;
        #pragma unroll
        for (int d = 0; d < DH_SZ; ++d) kvreg[d] += kp * row[64 + d];
    }
    float* outp = kvpart + ((long)blockIdx.x * M_SZ + t) * DH_SZ;
    #pragma unroll
    for (int d = 0; d < DH_SZ; d += 4) {
        float4 o = {kvreg[d], kvreg[d + 1], kvreg[d + 2], kvreg[d + 3]};
        *(float4*)(outp + d) = o;
    }
    kspart[(long)blockIdx.x * M_SZ + t] = ks;
}

__global__ __launch_bounds__(256) void reduce_parts(
    const float* __restrict__ kvpart, const float* __restrict__ kspart,
    float* __restrict__ kvfin, float* __restrict__ ksfin)
{
    const int i = blockIdx.x * 256 + threadIdx.x;
    if (i < KV_TOT) {
        const int bh  = i / (M_SZ * DH_SZ);
        const int rem = i % (M_SZ * DH_SZ);
        float sum = 0.f;
        #pragma unroll
        for (int p = 0; p < SPLIT; ++p)
            sum += kvpart[((long)(bh * SPLIT + p)) * (M_SZ * DH_SZ) + rem];
        kvfin[i] = sum;
    } else {
        const int j = i - KV_TOT;
        if (j < KS_TOT) {
            const int bh = j / M_SZ;
            const int m  = j % M_SZ;
            float sum = 0.f;
            #pragma unroll
            for (int p = 0; p < SPLIT; ++p)
                sum += kspart[(bh * SPLIT + p) * M_SZ + m];
            ksfin[j] = sum;
        }
    }
}

// ---------------------------------------------------------------------------
// Kernel 3: q' feature map + numerator/denominator -> att bf16 (unchanged)
// ---------------------------------------------------------------------------
__global__ __launch_bounds__(256) void attn_out(
    const __hip_bfloat16* __restrict__ qkv, const float* __restrict__ omega,
    const float* __restrict__ kvfin, const float* __restrict__ ksfin,
    __hip_bfloat16* __restrict__ att)
{
    const int t  = threadIdx.x;
    const int c  = blockIdx.x % CH3;
    const int bh = blockIdx.x / CH3;
    const int b  = bh / H_SZ, h = bh % H_SZ;
    __shared__ float kvs[M_SZ * (DH_SZ + 1)];
    __shared__ float kss[M_SZ];
    __shared__ float qps[M_SZ];
    __shared__ float pnum[M_SZ];
    __shared__ float row[132];
    __shared__ float wsum[4];

    float omr[DH_SZ];
    #pragma unroll
    for (int j = 0; j < DH_SZ; ++j) omr[j] = omega[j * M_SZ + t];
    for (int i = t; i < M_SZ * DH_SZ; i += 256)
        kvs[(i >> 6) * 65 + (i & 63)] = kvfin[(long)bh * (M_SZ * DH_SZ) + i];
    kss[t] = ksfin[bh * M_SZ + t];

    const int RPC = N_SZ / CH3;   // 512
    const int n0  = c * RPC;
    const int d = t & 63, p = t >> 6;
    for (int r = 0; r < RPC; ++r) {
        const long nrow = (long)(b * N_SZ + n0 + r);
        const long base = nrow * (3 * D_SZ);
        __syncthreads();
        if (t < 64) {
            const float qv = __bfloat162float(qkv[base + h * DH_SZ + t]);
            row[t] = qv;
            float ss = qv * qv;
            #pragma unroll
            for (int o = 32; o > 0; o >>= 1) ss += __shfl_xor(ss, o, 64);
            if (t == 0) row[128] = ss;
        }
        __syncthreads();
        const float nrm = row[128];
        float dot = 0.f;
        #pragma unroll
        for (int j = 0; j < DH_SZ; ++j) dot += row[j] * omr[j];
        const float qp = __expf(dot - 0.5f * nrm);
        qps[t] = qp;
        float pd = qp * kss[t];
        #pragma unroll
        for (int o = 32; o > 0; o >>= 1) pd += __shfl_xor(pd, o, 64);
        if ((t & 63) == 0) wsum[t >> 6] = pd;
        __syncthreads();
        float sacc = 0.f;
        const int m0 = p << 6;
        #pragma unroll 16
        for (int mm = 0; mm < 64; ++mm)
            sacc += qps[m0 + mm] * kvs[(m0 + mm) * 65 + d];
        pnum[t] = sacc;
        __syncthreads();
        if (t < 64) {
            const float den = wsum[0] + wsum[1] + wsum[2] + wsum[3] + 1e-6f;
            const float num = pnum[t] + pnum[t + 64] + pnum[t + 128] + pnum[t + 192];
            att[nrow * D_SZ + h * DH_SZ + t] = __float2bfloat16(num / den);
        }
    }
}

// ---------------------------------------------------------------------------
// Workspace (bytes), total 143,130,624 (<= 139MB layout that passed + 4MB):
//  X [0, 34,078,720):      xb bf16 33.5MB  ->  kvpart 33.5MB + kspart 0.5MB
//                          ->  att bf16 33.5MB   (phase-ordered aliasing)
//  qkv   [34,078,720, 134,742,016)  bf16 [16384,3072]
//  Y [134,742,016, 141,033,472):   Wqkv_t bf16 6MB  ->  kvfin 4MB + ksfin 64KB
//  Wout_t [141,033,472, 143,130,624) bf16 2MB
// ---------------------------------------------------------------------------
extern "C" void kernel_launch(void* const* d_in, const int* in_sizes, int n_in,
                              void* d_out, int out_size, void* d_ws, size_t ws_size,
                              hipStream_t stream)
{
    const float* x     = (const float*)d_in[0];
    const float* Wqkv  = (const float*)d_in[1];
    const float* bqkv  = (const float*)d_in[2];
    const float* Wout  = (const float*)d_in[3];
    const float* bout  = (const float*)d_in[4];
    const float* omega = (const float*)d_in[5];
    float* out = (float*)d_out;

    char* w = (char*)d_ws;
    u16*   xb      = (u16*)w;
    float* kvpart  = (float*)w;
    float* kspart  = (float*)(w + 33554432);
    __hip_bfloat16* att = (__hip_bfloat16*)w;
    u16*   qkv_u   = (u16*)(w + 34078720);
    __hip_bfloat16* qkv = (__hip_bfloat16*)qkv_u;
    u16*   Wqkv_t  = (u16*)(w + 134742016);
    float* kvfin   = (float*)(w + 134742016);
    float* ksfin   = (float*)(w + 134742016 + 4194304);
    u16*   Wout_t  = (u16*)(w + 141033472);

    // 0) input conversions
    cvt_f32_bf16<<<ROWS * D_SZ / (256 * 8), 256, 0, stream>>>(x, xb);
    {
        dim3 g(3 * D_SZ / 32, D_SZ / 32);
        transpose_cvt<<<g, 256, 0, stream>>>(Wqkv, Wqkv_t, D_SZ, 3 * D_SZ);
    }
    {
        dim3 g(D_SZ / 32, D_SZ / 32);
        transpose_cvt<<<g, 256, 0, stream>>>(Wout, Wout_t, D_SZ, D_SZ);
    }
    // 1) qkv = x @ Wqkv + bqkv  (bf16 MFMA, bf16 out)
    {
        dim3 g(3 * D_SZ / 128, ROWS / 128);
        gemm_mfma_bt<u16><<<g, 256, 0, stream>>>(xb, Wqkv_t, bqkv, qkv_u, 3 * D_SZ, D_SZ);
    }
    // 2) k' accumulation + reduce
    kv_accum<<<B_SZ * H_SZ * SPLIT, 256, 0, stream>>>(qkv, omega, kvpart, kspart);
    {
        int total = KV_TOT + KS_TOT;
        reduce_parts<<<(total + 255) / 256, 256, 0, stream>>>(kvpart, kspart, kvfin, ksfin);
    }
    // 3) q' feature map + numerator/denominator -> att (bf16)
    attn_out<<<B_SZ * H_SZ * CH3, 256, 0, stream>>>(qkv, omega, kvfin, ksfin, att);
    // 4) out = att @ Wout + bout  (bf16 MFMA, f32 out)
    {
        dim3 g(D_SZ / 128, ROWS / 128);
        gemm_mfma_bt<float><<<g, 256, 0, stream>>>((const u16*)att, Wout_t, bout, out, D_SZ, D_SZ);
    }
}

// Round 6
// 475.450 us; speedup vs baseline: 7.9744x; 3.9440x over previous
//
#include <hip/hip_runtime.h>
#include <hip/hip_bf16.h>

#define B_SZ 4
#define N_SZ 4096
#define D_SZ 1024
#define H_SZ 16
#define M_SZ 256
#define DH_SZ 64
#define ROWS (B_SZ * N_SZ)          // 16384
#define KSPLIT 4
#define QROWS 64
#define KV_TOT (64 * M_SZ * DH_SZ)  // 1048576
#define KS_TOT (64 * M_SZ)          // 16384

typedef unsigned short u16;
typedef __attribute__((ext_vector_type(8))) short bf16x8;
typedef __attribute__((ext_vector_type(4))) short s16x4;
typedef __attribute__((ext_vector_type(4))) float f32x4;

static __device__ inline u16 f2bf(float f) {
    __hip_bfloat16 h = __float2bfloat16(f);
    return *reinterpret_cast<u16*>(&h);
}
static __device__ inline float bf2f(u16 u) {
    return __bfloat162float(*reinterpret_cast<__hip_bfloat16*>(&u));
}

static __device__ inline void gl_lds16(const void* g, void* l) {
    void* gg = const_cast<void*>(g);
    __builtin_amdgcn_global_load_lds(
        (__attribute__((address_space(1))) void*)gg,
        (__attribute__((address_space(3))) void*)l, 16, 0, 0);
}

// ---------------------------------------------------------------------------
// convert f32 -> bf16 (8 elements/thread)
// ---------------------------------------------------------------------------
__global__ __launch_bounds__(256) void cvt_f32_bf16(
    const float* __restrict__ src, u16* __restrict__ dst)
{
    const long i = ((long)blockIdx.x * 256 + threadIdx.x) * 8;
    float4 v0 = *(const float4*)(src + i);
    float4 v1 = *(const float4*)(src + i + 4);
    union { u16 s[8]; bf16x8 v; } o;
    o.s[0] = f2bf(v0.x); o.s[1] = f2bf(v0.y); o.s[2] = f2bf(v0.z); o.s[3] = f2bf(v0.w);
    o.s[4] = f2bf(v1.x); o.s[5] = f2bf(v1.y); o.s[6] = f2bf(v1.z); o.s[7] = f2bf(v1.w);
    *(bf16x8*)(dst + i) = o.v;
}

// ---------------------------------------------------------------------------
// transpose + convert: src f32 [R][C] -> dst bf16 [C][R]
// ---------------------------------------------------------------------------
__global__ __launch_bounds__(256) void transpose_cvt(
    const float* __restrict__ src, u16* __restrict__ dst, int R, int C)
{
    __shared__ float tile[32][33];
    const int c0 = blockIdx.x * 32, r0 = blockIdx.y * 32;
    const int tx = threadIdx.x & 31, ty = threadIdx.x >> 5;   // 32 x 8
    #pragma unroll
    for (int p = 0; p < 4; ++p)
        tile[ty + 8 * p][tx] = src[(long)(r0 + ty + 8 * p) * C + c0 + tx];
    __syncthreads();
    #pragma unroll
    for (int p = 0; p < 4; ++p)
        dst[(long)(c0 + ty + 8 * p) * R + r0 + tx] = f2bf(tile[tx][ty + 8 * p]);
}

// ---------------------------------------------------------------------------
// MFMA GEMM (m97 structure): C[M,Nc] = A[M,K] @ Bt[Nc,K]^T + bias
// ---------------------------------------------------------------------------
template <typename OUT>
__global__ __launch_bounds__(256) void gemm_mfma_bt(
    const u16* __restrict__ A, const u16* __restrict__ Bt,
    const float* __restrict__ bias, OUT* __restrict__ C,
    int Nc, int K)
{
    __shared__ u16 As[128 * 32];
    __shared__ u16 Bs[128 * 32];
    const int t = threadIdx.x;
    const int w = t >> 6, l = t & 63;
    const int wr = w >> 1, wc = w & 1;
    const long brow = (long)blockIdx.y * 128;
    const long bcol = (long)blockIdx.x * 128;

    const int sr = l >> 2;
    const int sc = (l & 3) * 8;
    const u16* aS0 = A + (brow + w * 16 + sr) * (long)K + sc;
    const u16* aS1 = A + (brow + 64 + w * 16 + sr) * (long)K + sc;
    const u16* bS0 = Bt + (bcol + w * 16 + sr) * (long)K + sc;
    const u16* bS1 = Bt + (bcol + 64 + w * 16 + sr) * (long)K + sc;
    u16* aD0 = As + (w) * 512;
    u16* aD1 = As + (w + 4) * 512;
    u16* bD0 = Bs + (w) * 512;
    u16* bD1 = Bs + (w + 4) * 512;

    f32x4 acc[4][4];
    #pragma unroll
    for (int m = 0; m < 4; ++m)
        #pragma unroll
        for (int n = 0; n < 4; ++n)
            acc[m][n] = (f32x4){0.f, 0.f, 0.f, 0.f};

    const int fr = l & 15;
    const int fk = (l >> 4) * 8;

    for (int k0 = 0; k0 < K; k0 += 32) {
        __syncthreads();
        gl_lds16(aS0 + k0, aD0);
        gl_lds16(aS1 + k0, aD1);
        gl_lds16(bS0 + k0, bD0);
        gl_lds16(bS1 + k0, bD1);
        __syncthreads();
        bf16x8 af[4], bfv[4];
        #pragma unroll
        for (int m = 0; m < 4; ++m)
            af[m] = *(const bf16x8*)(As + (wr * 64 + m * 16 + fr) * 32 + fk);
        #pragma unroll
        for (int n = 0; n < 4; ++n)
            bfv[n] = *(const bf16x8*)(Bs + (wc * 64 + n * 16 + fr) * 32 + fk);
        #pragma unroll
        for (int m = 0; m < 4; ++m)
            #pragma unroll
            for (int n = 0; n < 4; ++n)
                acc[m][n] = __builtin_amdgcn_mfma_f32_16x16x32_bf16(
                    af[m], bfv[n], acc[m][n], 0, 0, 0);
    }

    const int fq = l >> 4;
    float bv[4];
    #pragma unroll
    for (int n = 0; n < 4; ++n)
        bv[n] = bias[bcol + wc * 64 + n * 16 + fr];
    #pragma unroll
    for (int m = 0; m < 4; ++m) {
        #pragma unroll
        for (int n = 0; n < 4; ++n) {
            const long col = bcol + wc * 64 + n * 16 + fr;
            #pragma unroll
            for (int r = 0; r < 4; ++r) {
                const long row = brow + wr * 64 + m * 16 + fq * 4 + r;
                const float v = acc[m][n][r] + bv[n];
                if constexpr (sizeof(OUT) == 2)
                    ((u16*)C)[row * Nc + col] = f2bf(v);
                else
                    ((float*)C)[row * Nc + col] = v;
            }
        }
    }
}

// ---------------------------------------------------------------------------
// kfeat: per (bh, split) block. Chunks of 64 rows:
//   MFMA1: S^T[m][n] = omegaT @ k^T  -> exp -> kT (LDS, sub-tiled)
//   MFMA2: kv[m][d] (+ ksum via ones-column) accumulated in registers.
// Fragment conventions: A rows / Bt rows sub-tiled [kc][row][32k];
// C: row=(l>>4)*4+r (A-side), col=l&15 (Bt-side). HW-verified in round 5.
// ---------------------------------------------------------------------------
__global__ __launch_bounds__(256) void kfeat(
    const u16* __restrict__ qkv, const u16* __restrict__ omT,
    float* __restrict__ kvpart, float* __restrict__ kspart)
{
    __shared__ u16 omTs[2][256][32];   // [d/32][m][d&31]
    __shared__ u16 kTs[2][256][32];    // [n/32][m][n&31]
    __shared__ u16 vTs[2][80][32];     // [n/32][d_ext][n&31]; row 64 = ones
    __shared__ u16 kcs[2][64][32];     // [d/32][n][d&31]
    __shared__ float norms[64];

    const int t = threadIdx.x;
    const int w = t >> 6, l = t & 63, fr = l & 15, fq = l >> 4;
    const int blk = blockIdx.x;
    const int s = blk & (KSPLIT - 1);
    const int bh = blk / KSPLIT;
    const int b = bh >> 4, h = bh & 15;
    const long rowbase = (long)b * N_SZ + s * (N_SZ / KSPLIT);

    for (int i = t; i < 2048; i += 256) {
        const int m = i >> 3, d0 = (i & 7) * 8;
        *(bf16x8*)&omTs[d0 >> 5][m][d0 & 31] = *(const bf16x8*)(omT + m * 64 + d0);
    }
    for (int i = t; i < 2 * 16 * 32; i += 256) {   // vTs rows 64..79
        const int kc = i >> 9, rr = (i >> 5) & 15, j = i & 31;
        vTs[kc][64 + rr][j] = (rr == 0) ? (u16)0x3F80 : (u16)0;
    }

    f32x4 acc2[4][5];
    #pragma unroll
    for (int mi = 0; mi < 4; ++mi)
        #pragma unroll
        for (int dt = 0; dt < 5; ++dt)
            acc2[mi][dt] = (f32x4){0.f, 0.f, 0.f, 0.f};

    for (int c = 0; c < (N_SZ / KSPLIT) / 64; ++c) {
        const long r0 = rowbase + c * 64;
        // ---- phase 1: stage kcs, vTs(0..63), norms ----
        for (int i = t; i < 512; i += 256) {
            const int n = i >> 3, d0 = (i & 7) * 8;
            *(bf16x8*)&kcs[d0 >> 5][n][d0 & 31] =
                *(const bf16x8*)(qkv + (r0 + n) * 3072 + D_SZ + h * 64 + d0);
            union { bf16x8 v; u16 s[8]; } uv;
            uv.v = *(const bf16x8*)(qkv + (r0 + n) * 3072 + 2 * D_SZ + h * 64 + d0);
            #pragma unroll
            for (int j = 0; j < 8; ++j) vTs[n >> 5][d0 + j][n & 31] = uv.s[j];
        }
        {
            const int r = t >> 2, p = t & 3;
            float ss = 0.f;
            const u16* krow = qkv + (r0 + r) * 3072 + D_SZ + h * 64 + p * 16;
            #pragma unroll
            for (int j = 0; j < 16; ++j) { const float v = bf2f(krow[j]); ss += v * v; }
            ss += __shfl_xor(ss, 1, 64);
            ss += __shfl_xor(ss, 2, 64);
            if (p == 0) norms[r] = 0.5f * ss;
        }
        __syncthreads();   // A
        // ---- phase 2: MFMA1 + exp + kT write ----
        f32x4 acc1[16];
        #pragma unroll
        for (int mt = 0; mt < 16; ++mt) acc1[mt] = (f32x4){0.f, 0.f, 0.f, 0.f};
        #pragma unroll
        for (int kc = 0; kc < 2; ++kc) {
            bf16x8 bfr = *(const bf16x8*)&kcs[kc][w * 16 + fr][fq * 8];
            #pragma unroll
            for (int mt = 0; mt < 16; ++mt) {
                bf16x8 afr = *(const bf16x8*)&omTs[kc][mt * 16 + fr][fq * 8];
                acc1[mt] = __builtin_amdgcn_mfma_f32_16x16x32_bf16(afr, bfr, acc1[mt], 0, 0, 0);
            }
        }
        const float nrm = norms[w * 16 + fr];
        #pragma unroll
        for (int mt = 0; mt < 16; ++mt) {
            #pragma unroll
            for (int r = 0; r < 4; ++r) {
                const float e = __expf(acc1[mt][r] - nrm);
                kTs[w >> 1][mt * 16 + fq * 4 + r][(w & 1) * 16 + fr] = f2bf(e);
            }
        }
        __syncthreads();   // B
        // ---- phase 3: MFMA2 accumulate kv + ksum ----
        #pragma unroll
        for (int kc = 0; kc < 2; ++kc) {
            bf16x8 bfv[5];
            #pragma unroll
            for (int dt = 0; dt < 5; ++dt)
                bfv[dt] = *(const bf16x8*)&vTs[kc][dt * 16 + fr][fq * 8];
            #pragma unroll
            for (int mi = 0; mi < 4; ++mi) {
                bf16x8 afr = *(const bf16x8*)&kTs[kc][w * 64 + mi * 16 + fr][fq * 8];
                #pragma unroll
                for (int dt = 0; dt < 5; ++dt)
                    acc2[mi][dt] = __builtin_amdgcn_mfma_f32_16x16x32_bf16(
                        afr, bfv[dt], acc2[mi][dt], 0, 0, 0);
            }
        }
        __syncthreads();   // C
    }

    float* kvp = kvpart + (long)blk * 16384;
    #pragma unroll
    for (int mi = 0; mi < 4; ++mi) {
        #pragma unroll
        for (int dt = 0; dt < 4; ++dt)
            #pragma unroll
            for (int r = 0; r < 4; ++r)
                kvp[(w * 64 + mi * 16 + fq * 4 + r) * 64 + dt * 16 + fr] = acc2[mi][dt][r];
        if (fr == 0) {
            #pragma unroll
            for (int r = 0; r < 4; ++r)
                kspart[blk * 256 + w * 64 + mi * 16 + fq * 4 + r] = acc2[mi][4][r];
        }
    }
}

// ---------------------------------------------------------------------------
// reduce2: sum KSPLIT partials -> kvT bf16 [bh][64 d][256 m], ksfin f32 [bh][256]
// ---------------------------------------------------------------------------
__global__ __launch_bounds__(256) void reduce2(
    const float* __restrict__ kvpart, const float* __restrict__ kspart,
    u16* __restrict__ kvT, float* __restrict__ ksfin)
{
    const int i = blockIdx.x * 256 + threadIdx.x;
    if (i < KV_TOT) {
        const int bh = i >> 14, d = (i >> 8) & 63, m = i & 255;
        float s = 0.f;
        #pragma unroll
        for (int p = 0; p < KSPLIT; ++p)
            s += kvpart[(long)(bh * KSPLIT + p) * 16384 + m * 64 + d];
        kvT[i] = f2bf(s);
    } else if (i < KV_TOT + KS_TOT) {
        const int j = i - KV_TOT, bh = j >> 8, m = j & 255;
        float s = 0.f;
        #pragma unroll
        for (int p = 0; p < KSPLIT; ++p)
            s += kspart[(bh * KSPLIT + p) * 256 + m];
        ksfin[j] = s;
    }
}

// ---------------------------------------------------------------------------
// qfeat: per (bh, 64-row tile):
//   MFMA1 S^T -> exp (regs) -> qps (LDS) ; den partial vs ksum broadcast
//   MFMA2 num = q' @ kvT ; out = num / (den + 1e-6) -> att bf16
// ---------------------------------------------------------------------------
__global__ __launch_bounds__(256) void qfeat(
    const u16* __restrict__ qkv, const u16* __restrict__ omT,
    const u16* __restrict__ kvT, const float* __restrict__ ksfin,
    u16* __restrict__ att)
{
    __shared__ u16 shA[16384];         // omTs [2][256][32] -> kvTs [8][64][32]
    __shared__ u16 qps[8][64][32];     // [m/32][n][m&31]
    __shared__ u16 qcs[2][64][32];     // [d/32][n][d&31]
    __shared__ float ksum[256];
    __shared__ float norms[64];
    __shared__ float den[64];

    const int t = threadIdx.x;
    const int w = t >> 6, l = t & 63, fr = l & 15, fq = l >> 4;
    const int blk = blockIdx.x;
    const int c = blk & 63;
    const int bh = blk >> 6;
    const int b = bh >> 4, h = bh & 15;
    const long r0 = (long)b * N_SZ + c * QROWS;

    for (int i = t; i < 2048; i += 256) {   // omTs: shA[kc*8192 + m*32 + (d&31)]
        const int m = i >> 3, d0 = (i & 7) * 8;
        *(bf16x8*)&shA[(d0 >> 5) * 8192 + m * 32 + (d0 & 31)] =
            *(const bf16x8*)(omT + m * 64 + d0);
    }
    for (int i = t; i < 512; i += 256) {
        const int n = i >> 3, d0 = (i & 7) * 8;
        *(bf16x8*)&qcs[d0 >> 5][n][d0 & 31] =
            *(const bf16x8*)(qkv + (r0 + n) * 3072 + h * 64 + d0);
    }
    ksum[t] = ksfin[bh * 256 + t];
    {
        const int r = t >> 2, p = t & 3;
        float ss = 0.f;
        const u16* qrow = qkv + (r0 + r) * 3072 + h * 64 + p * 16;
        #pragma unroll
        for (int j = 0; j < 16; ++j) { const float v = bf2f(qrow[j]); ss += v * v; }
        ss += __shfl_xor(ss, 1, 64);
        ss += __shfl_xor(ss, 2, 64);
        if (p == 0) norms[r] = 0.5f * ss;
    }
    __syncthreads();

    // MFMA1: S^T[m][n], wave w -> n-tile w, 16 m-tiles
    f32x4 acc1[16];
    #pragma unroll
    for (int mt = 0; mt < 16; ++mt) acc1[mt] = (f32x4){0.f, 0.f, 0.f, 0.f};
    #pragma unroll
    for (int kc = 0; kc < 2; ++kc) {
        bf16x8 bfr = *(const bf16x8*)&qcs[kc][w * 16 + fr][fq * 8];
        #pragma unroll
        for (int mt = 0; mt < 16; ++mt) {
            bf16x8 afr = *(const bf16x8*)&shA[kc * 8192 + (mt * 16 + fr) * 32 + fq * 8];
            acc1[mt] = __builtin_amdgcn_mfma_f32_16x16x32_bf16(afr, bfr, acc1[mt], 0, 0, 0);
        }
    }
    const float nrm = norms[w * 16 + fr];
    float denp = 0.f;
    #pragma unroll
    for (int mt = 0; mt < 16; ++mt) {
        union { s16x4 v; u16 s[4]; } pk;
        #pragma unroll
        for (int r = 0; r < 4; ++r) {
            const float e = __expf(acc1[mt][r] - nrm);
            denp += e * ksum[mt * 16 + fq * 4 + r];
            pk.s[r] = f2bf(e);
        }
        *(s16x4*)&qps[mt >> 1][w * 16 + fr][(mt & 1) * 16 + fq * 4] = pk.v;
    }
    __syncthreads();   // qps complete; omTs reads done

    // stage kvTs into shA: shA[kc*2048 + d*32 + (m&31)]
    const u16* kvb = kvT + bh * 16384;
    for (int i = t; i < 2048; i += 256) {
        const int d = i >> 5, m0 = (i & 31) * 8;
        *(bf16x8*)&shA[(m0 >> 5) * 2048 + d * 32 + (m0 & 31)] =
            *(const bf16x8*)(kvb + d * 256 + m0);
    }
    denp += __shfl_xor(denp, 16, 64);
    denp += __shfl_xor(denp, 32, 64);
    if (l < 16) den[w * 16 + fr] = denp;
    __syncthreads();

    // MFMA2: num[n][d], wave w -> n-tile w
    f32x4 acc3[4];
    #pragma unroll
    for (int dt = 0; dt < 4; ++dt) acc3[dt] = (f32x4){0.f, 0.f, 0.f, 0.f};
    #pragma unroll
    for (int kc = 0; kc < 8; ++kc) {
        bf16x8 afr = *(const bf16x8*)&qps[kc][w * 16 + fr][fq * 8];
        #pragma unroll
        for (int dt = 0; dt < 4; ++dt) {
            bf16x8 bfr = *(const bf16x8*)&shA[kc * 2048 + (dt * 16 + fr) * 32 + fq * 8];
            acc3[dt] = __builtin_amdgcn_mfma_f32_16x16x32_bf16(afr, bfr, acc3[dt], 0, 0, 0);
        }
    }
    #pragma unroll
    for (int r = 0; r < 4; ++r) {
        const int n = w * 16 + fq * 4 + r;
        const float dn = den[n] + 1e-6f;
        #pragma unroll
        for (int dt = 0; dt < 4; ++dt)
            att[(r0 + n) * 1024 + h * 64 + dt * 16 + fr] = f2bf(acc3[dt][r] / dn);
    }
}

// ---------------------------------------------------------------------------
// Workspace (bytes), total 143,163,392:
//  X [0, 34,078,720):  xb(33.5M) -> kvpart(16.8M)+kspart(256K) -> att(33.5M)
//  qkv [34,078,720, 134,742,016) bf16 [16384][3072]
//  Y [134,742,016, 141,033,472): Wqkv_t(6M) -> kvT(2M)+ksfin(64K)
//  Wout_t [141,033,472, +2M) ; omT [143,130,624, +32K)
// ---------------------------------------------------------------------------
extern "C" void kernel_launch(void* const* d_in, const int* in_sizes, int n_in,
                              void* d_out, int out_size, void* d_ws, size_t ws_size,
                              hipStream_t stream)
{
    const float* x     = (const float*)d_in[0];
    const float* Wqkv  = (const float*)d_in[1];
    const float* bqkv  = (const float*)d_in[2];
    const float* Wout  = (const float*)d_in[3];
    const float* bout  = (const float*)d_in[4];
    const float* omega = (const float*)d_in[5];
    float* out = (float*)d_out;

    char* wp = (char*)d_ws;
    u16*   xb     = (u16*)wp;
    float* kvpart = (float*)wp;
    float* kspart = (float*)(wp + 16777216);
    u16*   att    = (u16*)wp;
    u16*   qkv    = (u16*)(wp + 34078720);
    u16*   Wqkv_t = (u16*)(wp + 134742016);
    u16*   kvT    = (u16*)(wp + 134742016);
    float* ksfin  = (float*)(wp + 134742016 + 2097152);
    u16*   Wout_t = (u16*)(wp + 141033472);
    u16*   omT    = (u16*)(wp + 143130624);

    cvt_f32_bf16<<<ROWS * D_SZ / (256 * 8), 256, 0, stream>>>(x, xb);
    {
        dim3 g(3 * D_SZ / 32, D_SZ / 32);
        transpose_cvt<<<g, 256, 0, stream>>>(Wqkv, Wqkv_t, D_SZ, 3 * D_SZ);
    }
    {
        dim3 g(D_SZ / 32, D_SZ / 32);
        transpose_cvt<<<g, 256, 0, stream>>>(Wout, Wout_t, D_SZ, D_SZ);
    }
    {
        dim3 g(M_SZ / 32, DH_SZ / 32);
        transpose_cvt<<<g, 256, 0, stream>>>(omega, omT, DH_SZ, M_SZ);
    }
    {
        dim3 g(3 * D_SZ / 128, ROWS / 128);
        gemm_mfma_bt<u16><<<g, 256, 0, stream>>>(xb, Wqkv_t, bqkv, qkv, 3 * D_SZ, D_SZ);
    }
    kfeat<<<64 * KSPLIT, 256, 0, stream>>>(qkv, omT, kvpart, kspart);
    {
        int total = KV_TOT + KS_TOT;
        reduce2<<<(total + 255) / 256, 256, 0, stream>>>(kvpart, kspart, kvT, ksfin);
    }
    qfeat<<<64 * 64, 256, 0, stream>>>(qkv, omT, kvT, ksfin, att);
    {
        dim3 g(D_SZ / 128, ROWS / 128);
        gemm_mfma_bt<float><<<g, 256, 0, stream>>>(att, Wout_t, bout, out, D_SZ, D_SZ);
    }
}

// Round 7
// 456.557 us; speedup vs baseline: 8.3044x; 1.0414x over previous
//
#include <hip/hip_runtime.h>
#include <hip/hip_bf16.h>

#define B_SZ 4
#define N_SZ 4096
#define D_SZ 1024
#define H_SZ 16
#define M_SZ 256
#define DH_SZ 64
#define ROWS (B_SZ * N_SZ)          // 16384
#define KSPLIT 4
#define KV_TOT (64 * M_SZ * DH_SZ)  // 1048576
#define KS_TOT (64 * M_SZ)          // 16384

typedef unsigned short u16;
typedef __attribute__((ext_vector_type(8))) short bf16x8;
typedef __attribute__((ext_vector_type(4))) short s16x4;
typedef __attribute__((ext_vector_type(4))) float f32x4;

static __device__ inline u16 f2bf(float f) {
    __hip_bfloat16 h = __float2bfloat16(f);
    return *reinterpret_cast<u16*>(&h);
}
static __device__ inline float bf2f(u16 u) {
    return __bfloat162float(*reinterpret_cast<__hip_bfloat16*>(&u));
}

static __device__ inline void gl_lds16(const void* g, void* l) {
    void* gg = const_cast<void*>(g);
    __builtin_amdgcn_global_load_lds(
        (__attribute__((address_space(1))) void*)gg,
        (__attribute__((address_space(3))) void*)l, 16, 0, 0);
}

// ---------------------------------------------------------------------------
// convert f32 -> bf16 (8 elements/thread)
// ---------------------------------------------------------------------------
__global__ __launch_bounds__(256) void cvt_f32_bf16(
    const float* __restrict__ src, u16* __restrict__ dst)
{
    const long i = ((long)blockIdx.x * 256 + threadIdx.x) * 8;
    float4 v0 = *(const float4*)(src + i);
    float4 v1 = *(const float4*)(src + i + 4);
    union { u16 s[8]; bf16x8 v; } o;
    o.s[0] = f2bf(v0.x); o.s[1] = f2bf(v0.y); o.s[2] = f2bf(v0.z); o.s[3] = f2bf(v0.w);
    o.s[4] = f2bf(v1.x); o.s[5] = f2bf(v1.y); o.s[6] = f2bf(v1.z); o.s[7] = f2bf(v1.w);
    *(bf16x8*)(dst + i) = o.v;
}

// ---------------------------------------------------------------------------
// transpose + convert: src f32 [R][C] -> dst bf16 [C][R]
// ---------------------------------------------------------------------------
__global__ __launch_bounds__(256) void transpose_cvt(
    const float* __restrict__ src, u16* __restrict__ dst, int R, int C)
{
    __shared__ float tile[32][33];
    const int c0 = blockIdx.x * 32, r0 = blockIdx.y * 32;
    const int tx = threadIdx.x & 31, ty = threadIdx.x >> 5;   // 32 x 8
    #pragma unroll
    for (int p = 0; p < 4; ++p)
        tile[ty + 8 * p][tx] = src[(long)(r0 + ty + 8 * p) * C + c0 + tx];
    __syncthreads();
    #pragma unroll
    for (int p = 0; p < 4; ++p)
        dst[(long)(c0 + ty + 8 * p) * R + r0 + tx] = f2bf(tile[tx][ty + 8 * p]);
}

// ---------------------------------------------------------------------------
// MFMA GEMM (m97 structure): C[M,Nc] = A[M,K] @ Bt[Nc,K]^T + bias  (unchanged)
// ---------------------------------------------------------------------------
template <typename OUT>
__global__ __launch_bounds__(256) void gemm_mfma_bt(
    const u16* __restrict__ A, const u16* __restrict__ Bt,
    const float* __restrict__ bias, OUT* __restrict__ C,
    int Nc, int K)
{
    __shared__ u16 As[128 * 32];
    __shared__ u16 Bs[128 * 32];
    const int t = threadIdx.x;
    const int w = t >> 6, l = t & 63;
    const int wr = w >> 1, wc = w & 1;
    const long brow = (long)blockIdx.y * 128;
    const long bcol = (long)blockIdx.x * 128;

    const int sr = l >> 2;
    const int sc = (l & 3) * 8;
    const u16* aS0 = A + (brow + w * 16 + sr) * (long)K + sc;
    const u16* aS1 = A + (brow + 64 + w * 16 + sr) * (long)K + sc;
    const u16* bS0 = Bt + (bcol + w * 16 + sr) * (long)K + sc;
    const u16* bS1 = Bt + (bcol + 64 + w * 16 + sr) * (long)K + sc;
    u16* aD0 = As + (w) * 512;
    u16* aD1 = As + (w + 4) * 512;
    u16* bD0 = Bs + (w) * 512;
    u16* bD1 = Bs + (w + 4) * 512;

    f32x4 acc[4][4];
    #pragma unroll
    for (int m = 0; m < 4; ++m)
        #pragma unroll
        for (int n = 0; n < 4; ++n)
            acc[m][n] = (f32x4){0.f, 0.f, 0.f, 0.f};

    const int fr = l & 15;
    const int fk = (l >> 4) * 8;

    for (int k0 = 0; k0 < K; k0 += 32) {
        __syncthreads();
        gl_lds16(aS0 + k0, aD0);
        gl_lds16(aS1 + k0, aD1);
        gl_lds16(bS0 + k0, bD0);
        gl_lds16(bS1 + k0, bD1);
        __syncthreads();
        bf16x8 af[4], bfv[4];
        #pragma unroll
        for (int m = 0; m < 4; ++m)
            af[m] = *(const bf16x8*)(As + (wr * 64 + m * 16 + fr) * 32 + fk);
        #pragma unroll
        for (int n = 0; n < 4; ++n)
            bfv[n] = *(const bf16x8*)(Bs + (wc * 64 + n * 16 + fr) * 32 + fk);
        #pragma unroll
        for (int m = 0; m < 4; ++m)
            #pragma unroll
            for (int n = 0; n < 4; ++n)
                acc[m][n] = __builtin_amdgcn_mfma_f32_16x16x32_bf16(
                    af[m], bfv[n], acc[m][n], 0, 0, 0);
    }

    const int fq = l >> 4;
    float bv[4];
    #pragma unroll
    for (int n = 0; n < 4; ++n)
        bv[n] = bias[bcol + wc * 64 + n * 16 + fr];
    #pragma unroll
    for (int m = 0; m < 4; ++m) {
        #pragma unroll
        for (int n = 0; n < 4; ++n) {
            const long col = bcol + wc * 64 + n * 16 + fr;
            #pragma unroll
            for (int r = 0; r < 4; ++r) {
                const long row = brow + wr * 64 + m * 16 + fq * 4 + r;
                const float v = acc[m][n][r] + bv[n];
                if constexpr (sizeof(OUT) == 2)
                    ((u16*)C)[row * Nc + col] = f2bf(v);
                else
                    ((float*)C)[row * Nc + col] = v;
            }
        }
    }
}

// ---------------------------------------------------------------------------
// kfeat (512 thr, 8 waves): per (bh, split) block, 8 chunks x 128 rows.
//   P1 stage kcs/vTs/norms from prefetched regs | P2 MFMA1 S^T = omT @ k^T
//   P3 exp -> kTs | P4 MFMA2 kv (+ksum via ones col) accumulate in regs.
// LDS: omTs 32K + kTbuf 64K (tail 16K doubles as kcs) + vTs 20K = ~116.5KB
// ---------------------------------------------------------------------------
__global__ __launch_bounds__(512) void kfeat(
    const u16* __restrict__ qkv, const u16* __restrict__ omT,
    float* __restrict__ kvpart, float* __restrict__ kspart)
{
    __shared__ u16 omTs[2][256][32];   // [d/32][m][d&31]
    __shared__ u16 kTbuf[32768];       // kTs[4][256][32]; +24576 = kcs[2][128][32]
    __shared__ u16 vTs[4][80][32];     // [n/32][d_ext][n&31]; rows 64..79: ones/zeros
    __shared__ float norms[128];

    const int t = threadIdx.x;
    const int w = t >> 6, l = t & 63, fr = l & 15, fq = l >> 4;
    const int blk = blockIdx.x;
    const int s = blk & (KSPLIT - 1), bh = blk >> 2;
    const int b = bh >> 4, h = bh & 15;
    const long rowbase = (long)b * N_SZ + s * (N_SZ / KSPLIT);

    const int pn = t >> 2, pd = (t & 3) * 16;
    const u16* kp = qkv + (rowbase + pn) * 3072 + D_SZ + h * 64 + pd;
    const u16* vp = qkv + (rowbase + pn) * 3072 + 2 * D_SZ + h * 64 + pd;
    bf16x8 pk0 = *(const bf16x8*)kp, pk1 = *(const bf16x8*)(kp + 8);
    bf16x8 pv0 = *(const bf16x8*)vp, pv1 = *(const bf16x8*)(vp + 8);

    for (int i = t; i < 2048; i += 512) {
        const int m = i >> 3, d0 = (i & 7) * 8;
        *(bf16x8*)&omTs[d0 >> 5][m][d0 & 31] = *(const bf16x8*)(omT + m * 64 + d0);
    }
    for (int i = t; i < 2048; i += 512) {
        const int kc = i >> 9, rr = (i >> 5) & 15, j = i & 31;
        vTs[kc][64 + rr][j] = (rr == 0) ? (u16)0x3F80 : (u16)0;
    }

    f32x4 acc2[2][5];
    #pragma unroll
    for (int mi = 0; mi < 2; ++mi)
        #pragma unroll
        for (int dt = 0; dt < 5; ++dt)
            acc2[mi][dt] = (f32x4){0.f, 0.f, 0.f, 0.f};

    u16* kcs = kTbuf + 24576;

    for (int c = 0; c < 8; ++c) {
        // ---- P1: stage from regs ----
        *(bf16x8*)(kcs + (pd >> 5) * 4096 + pn * 32 + (pd & 31)) = pk0;
        *(bf16x8*)(kcs + (pd >> 5) * 4096 + pn * 32 + (pd & 31) + 8) = pk1;
        union { bf16x8 v; u16 u[8]; } uk0, uk1, uv0, uv1;
        uk0.v = pk0; uk1.v = pk1; uv0.v = pv0; uv1.v = pv1;
        #pragma unroll
        for (int j = 0; j < 8; ++j) {
            vTs[pn >> 5][pd + j][pn & 31] = uv0.u[j];
            vTs[pn >> 5][pd + 8 + j][pn & 31] = uv1.u[j];
        }
        float ss = 0.f;
        #pragma unroll
        for (int j = 0; j < 8; ++j) {
            float a = bf2f(uk0.u[j]), bb = bf2f(uk1.u[j]);
            ss += a * a + bb * bb;
        }
        ss += __shfl_xor(ss, 1, 64);
        ss += __shfl_xor(ss, 2, 64);
        if ((t & 3) == 0) norms[pn] = 0.5f * ss;
        __syncthreads();   // A
        // prefetch next chunk (overlaps P2..P4)
        if (c < 7) {
            const long off = (long)(c + 1) * 128 * 3072;
            pk0 = *(const bf16x8*)(kp + off);
            pk1 = *(const bf16x8*)(kp + off + 8);
            pv0 = *(const bf16x8*)(vp + off);
            pv1 = *(const bf16x8*)(vp + off + 8);
        }
        // ---- P2: MFMA1 S^T[m][n] ----
        f32x4 acc1[16];
        #pragma unroll
        for (int mt = 0; mt < 16; ++mt) acc1[mt] = (f32x4){0.f, 0.f, 0.f, 0.f};
        #pragma unroll
        for (int kc = 0; kc < 2; ++kc) {
            bf16x8 bfr = *(const bf16x8*)(kcs + kc * 4096 + (w * 16 + fr) * 32 + fq * 8);
            #pragma unroll
            for (int mt = 0; mt < 16; ++mt) {
                bf16x8 afr = *(const bf16x8*)&omTs[kc][mt * 16 + fr][fq * 8];
                acc1[mt] = __builtin_amdgcn_mfma_f32_16x16x32_bf16(afr, bfr, acc1[mt], 0, 0, 0);
            }
        }
        __syncthreads();   // B (MFMA1 done before kT writes clobber kcs region)
        // ---- P3: exp -> kTs ----
        const float nrm = norms[w * 16 + fr];
        #pragma unroll
        for (int mt = 0; mt < 16; ++mt) {
            #pragma unroll
            for (int r = 0; r < 4; ++r) {
                const float e = __expf(acc1[mt][r] - nrm);
                kTbuf[(w >> 1) * 8192 + (mt * 16 + fq * 4 + r) * 32 + (w & 1) * 16 + fr] = f2bf(e);
            }
        }
        __syncthreads();   // C
        // ---- P4: MFMA2 accumulate kv + ksum ----
        #pragma unroll
        for (int kc = 0; kc < 4; ++kc) {
            bf16x8 bfv[5];
            #pragma unroll
            for (int dt = 0; dt < 5; ++dt)
                bfv[dt] = *(const bf16x8*)&vTs[kc][dt * 16 + fr][fq * 8];
            #pragma unroll
            for (int mi = 0; mi < 2; ++mi) {
                bf16x8 afr = *(const bf16x8*)(kTbuf + kc * 8192 + ((w * 2 + mi) * 16 + fr) * 32 + fq * 8);
                #pragma unroll
                for (int dt = 0; dt < 5; ++dt)
                    acc2[mi][dt] = __builtin_amdgcn_mfma_f32_16x16x32_bf16(
                        afr, bfv[dt], acc2[mi][dt], 0, 0, 0);
            }
        }
        __syncthreads();   // D
    }

    float* kvp = kvpart + (long)blk * 16384;
    #pragma unroll
    for (int mi = 0; mi < 2; ++mi) {
        const int m0 = (w * 2 + mi) * 16 + fq * 4;
        #pragma unroll
        for (int dt = 0; dt < 4; ++dt)
            #pragma unroll
            for (int r = 0; r < 4; ++r)
                kvp[(m0 + r) * 64 + dt * 16 + fr] = acc2[mi][dt][r];
        if (fr == 0) {
            #pragma unroll
            for (int r = 0; r < 4; ++r)
                kspart[blk * 256 + m0 + r] = acc2[mi][4][r];
        }
    }
}

// ---------------------------------------------------------------------------
// reduce2: sum KSPLIT partials -> kvT bf16 [bh][64 d][256 m], ksfin f32
// ---------------------------------------------------------------------------
__global__ __launch_bounds__(256) void reduce2(
    const float* __restrict__ kvpart, const float* __restrict__ kspart,
    u16* __restrict__ kvT, float* __restrict__ ksfin)
{
    const int i = blockIdx.x * 256 + threadIdx.x;
    if (i < KV_TOT) {
        const int bh = i >> 14, d = (i >> 8) & 63, m = i & 255;
        float s = 0.f;
        #pragma unroll
        for (int p = 0; p < KSPLIT; ++p)
            s += kvpart[(long)(bh * KSPLIT + p) * 16384 + m * 64 + d];
        kvT[i] = f2bf(s);
    } else if (i < KV_TOT + KS_TOT) {
        const int j = i - KV_TOT, bh = j >> 8, m = j & 255;
        float s = 0.f;
        #pragma unroll
        for (int p = 0; p < KSPLIT; ++p)
            s += kspart[(bh * KSPLIT + p) * 256 + m];
        ksfin[j] = s;
    }
}

// ---------------------------------------------------------------------------
// qfeat (512 thr, 8 waves): per (bh, slice) block, 4 chunks x 128 rows.
//   P1 stage qcs/norms | P2 MFMA1 S^T | P3 exp -> qps, den | P4 MFMA2 num, att
// LDS: omTs 32K + kvTs 32K + qbuf 64K (tail 16K doubles as qcs) = ~130KB
// ---------------------------------------------------------------------------
__global__ __launch_bounds__(512) void qfeat(
    const u16* __restrict__ qkv, const u16* __restrict__ omT,
    const u16* __restrict__ kvT, const float* __restrict__ ksfin,
    u16* __restrict__ att)
{
    __shared__ u16 omTs[2][256][32];   // [d/32][m][d&31]
    __shared__ u16 kvTs[8][64][32];    // [m/32][d][m&31]
    __shared__ u16 qbuf[32768];        // qps[8][128][32]; +24576 = qcs[2][128][32]
    __shared__ float ksum[256];
    __shared__ float norms[128];
    __shared__ float den[128];

    const int t = threadIdx.x;
    const int w = t >> 6, l = t & 63, fr = l & 15, fq = l >> 4;
    const int blk = blockIdx.x;
    const int slice = blk & 7, bh = blk >> 3;
    const int b = bh >> 4, h = bh & 15;
    const long rowbase = (long)b * N_SZ + slice * 512;

    const int pn = t >> 2, pd = (t & 3) * 16;
    const u16* qp = qkv + (rowbase + pn) * 3072 + h * 64 + pd;
    bf16x8 pq0 = *(const bf16x8*)qp, pq1 = *(const bf16x8*)(qp + 8);

    for (int i = t; i < 2048; i += 512) {
        const int m = i >> 3, d0 = (i & 7) * 8;
        *(bf16x8*)&omTs[d0 >> 5][m][d0 & 31] = *(const bf16x8*)(omT + m * 64 + d0);
    }
    const u16* kvb = kvT + bh * 16384;
    for (int i = t; i < 2048; i += 512) {
        const int d = i >> 5, m0 = (i & 31) * 8;
        *(bf16x8*)&kvTs[m0 >> 5][d][m0 & 31] = *(const bf16x8*)(kvb + d * 256 + m0);
    }
    if (t < 256) ksum[t] = ksfin[bh * 256 + t];

    u16* qcs = qbuf + 24576;

    for (int c = 0; c < 4; ++c) {
        // ---- P1: stage qcs + norms from regs ----
        *(bf16x8*)(qcs + (pd >> 5) * 4096 + pn * 32 + (pd & 31)) = pq0;
        *(bf16x8*)(qcs + (pd >> 5) * 4096 + pn * 32 + (pd & 31) + 8) = pq1;
        union { bf16x8 v; u16 u[8]; } uq0, uq1;
        uq0.v = pq0; uq1.v = pq1;
        float ss = 0.f;
        #pragma unroll
        for (int j = 0; j < 8; ++j) {
            float a = bf2f(uq0.u[j]), bb = bf2f(uq1.u[j]);
            ss += a * a + bb * bb;
        }
        ss += __shfl_xor(ss, 1, 64);
        ss += __shfl_xor(ss, 2, 64);
        if ((t & 3) == 0) norms[pn] = 0.5f * ss;
        __syncthreads();   // A
        if (c < 3) {
            const long off = (long)(c + 1) * 128 * 3072;
            pq0 = *(const bf16x8*)(qp + off);
            pq1 = *(const bf16x8*)(qp + off + 8);
        }
        // ---- P2: MFMA1 S^T[m][n] ----
        f32x4 acc1[16];
        #pragma unroll
        for (int mt = 0; mt < 16; ++mt) acc1[mt] = (f32x4){0.f, 0.f, 0.f, 0.f};
        #pragma unroll
        for (int kc = 0; kc < 2; ++kc) {
            bf16x8 bfr = *(const bf16x8*)(qcs + kc * 4096 + (w * 16 + fr) * 32 + fq * 8);
            #pragma unroll
            for (int mt = 0; mt < 16; ++mt) {
                bf16x8 afr = *(const bf16x8*)&omTs[kc][mt * 16 + fr][fq * 8];
                acc1[mt] = __builtin_amdgcn_mfma_f32_16x16x32_bf16(afr, bfr, acc1[mt], 0, 0, 0);
            }
        }
        __syncthreads();   // B (MFMA1 done before qps writes clobber qcs region)
        // ---- P3: exp -> qps, den ----
        const float nrm = norms[w * 16 + fr];
        float denp = 0.f;
        #pragma unroll
        for (int mt = 0; mt < 16; ++mt) {
            union { s16x4 v; u16 u[4]; } pk;
            #pragma unroll
            for (int r = 0; r < 4; ++r) {
                const float e = __expf(acc1[mt][r] - nrm);
                denp += e * ksum[mt * 16 + fq * 4 + r];
                pk.u[r] = f2bf(e);
            }
            *(s16x4*)(qbuf + (mt >> 1) * 4096 + (w * 16 + fr) * 32 + (mt & 1) * 16 + fq * 4) = pk.v;
        }
        denp += __shfl_xor(denp, 16, 64);
        denp += __shfl_xor(denp, 32, 64);
        if (l < 16) den[w * 16 + fr] = denp;
        __syncthreads();   // C
        // ---- P4: MFMA2 num[n][d], att write ----
        f32x4 acc3[4];
        #pragma unroll
        for (int dt = 0; dt < 4; ++dt) acc3[dt] = (f32x4){0.f, 0.f, 0.f, 0.f};
        #pragma unroll
        for (int kc = 0; kc < 8; ++kc) {
            bf16x8 afr = *(const bf16x8*)(qbuf + kc * 4096 + (w * 16 + fr) * 32 + fq * 8);
            #pragma unroll
            for (int dt = 0; dt < 4; ++dt) {
                bf16x8 bfr = *(const bf16x8*)&kvTs[kc][dt * 16 + fr][fq * 8];
                acc3[dt] = __builtin_amdgcn_mfma_f32_16x16x32_bf16(afr, bfr, acc3[dt], 0, 0, 0);
            }
        }
        #pragma unroll
        for (int r = 0; r < 4; ++r) {
            const int n = w * 16 + fq * 4 + r;
            const float dn = den[n] + 1e-6f;
            #pragma unroll
            for (int dt = 0; dt < 4; ++dt)
                att[(rowbase + c * 128 + n) * 1024 + h * 64 + dt * 16 + fr] =
                    f2bf(acc3[dt][r] / dn);
        }
        __syncthreads();   // D
    }
}

// ---------------------------------------------------------------------------
// Workspace (bytes), total 143,163,392:
//  X [0, 34,078,720):  xb(33.5M) -> kvpart(16.8M)+kspart(256K) -> att(33.5M)
//  qkv [34,078,720, 134,742,016) bf16 [16384][3072]
//  Y [134,742,016, 141,033,472): Wqkv_t(6M) -> kvT(2M)+ksfin(64K)
//  Wout_t [141,033,472, +2M) ; omT [143,130,624, +32K)
// ---------------------------------------------------------------------------
extern "C" void kernel_launch(void* const* d_in, const int* in_sizes, int n_in,
                              void* d_out, int out_size, void* d_ws, size_t ws_size,
                              hipStream_t stream)
{
    const float* x     = (const float*)d_in[0];
    const float* Wqkv  = (const float*)d_in[1];
    const float* bqkv  = (const float*)d_in[2];
    const float* Wout  = (const float*)d_in[3];
    const float* bout  = (const float*)d_in[4];
    const float* omega = (const float*)d_in[5];
    float* out = (float*)d_out;

    char* wp = (char*)d_ws;
    u16*   xb     = (u16*)wp;
    float* kvpart = (float*)wp;
    float* kspart = (float*)(wp + 16777216);
    u16*   att    = (u16*)wp;
    u16*   qkv    = (u16*)(wp + 34078720);
    u16*   Wqkv_t = (u16*)(wp + 134742016);
    u16*   kvT    = (u16*)(wp + 134742016);
    float* ksfin  = (float*)(wp + 134742016 + 2097152);
    u16*   Wout_t = (u16*)(wp + 141033472);
    u16*   omT    = (u16*)(wp + 143130624);

    cvt_f32_bf16<<<ROWS * D_SZ / (256 * 8), 256, 0, stream>>>(x, xb);
    {
        dim3 g(3 * D_SZ / 32, D_SZ / 32);
        transpose_cvt<<<g, 256, 0, stream>>>(Wqkv, Wqkv_t, D_SZ, 3 * D_SZ);
    }
    {
        dim3 g(D_SZ / 32, D_SZ / 32);
        transpose_cvt<<<g, 256, 0, stream>>>(Wout, Wout_t, D_SZ, D_SZ);
    }
    {
        dim3 g(M_SZ / 32, DH_SZ / 32);
        transpose_cvt<<<g, 256, 0, stream>>>(omega, omT, DH_SZ, M_SZ);
    }
    {
        dim3 g(3 * D_SZ / 128, ROWS / 128);
        gemm_mfma_bt<u16><<<g, 256, 0, stream>>>(xb, Wqkv_t, bqkv, qkv, 3 * D_SZ, D_SZ);
    }
    kfeat<<<64 * KSPLIT, 512, 0, stream>>>(qkv, omT, kvpart, kspart);
    {
        int total = KV_TOT + KS_TOT;
        reduce2<<<(total + 255) / 256, 256, 0, stream>>>(kvpart, kspart, kvT, ksfin);
    }
    qfeat<<<64 * 8, 512, 0, stream>>>(qkv, omT, kvT, ksfin, att);
    {
        dim3 g(D_SZ / 128, ROWS / 128);
        gemm_mfma_bt<float><<<g, 256, 0, stream>>>(att, Wout_t, bout, out, D_SZ, D_SZ);
    }
}